// Round 13
// baseline (349.838 us; speedup 1.0000x reference)
//
#include <hip/hip_runtime.h>

#define B_ 512
#define S_ 512
#define E_ 128
#define H_ 100
#define T_ 64
#define V_ 100000
#define BS_ (B_*S_)

typedef __attribute__((ext_vector_type(8))) short bf16x8;
typedef __attribute__((ext_vector_type(4))) float f32x4;
typedef __attribute__((ext_vector_type(2))) float f32x2;
union U16x4 { uint4 u; bf16x8 s; };

__device__ __forceinline__ unsigned f2bf1(float x){
    unsigned u = __float_as_uint(x);
    return (u + 0x7FFFu + ((u>>16)&1u)) >> 16;
}
__device__ __forceinline__ float bf2f(unsigned short h){
    return __uint_as_float(((unsigned)h)<<16);
}
__device__ __forceinline__ float rfl_f(float x){
    return __uint_as_float(__builtin_amdgcn_readfirstlane(__float_as_uint(x)));
}
__device__ __forceinline__ unsigned addpack3(unsigned a, unsigned b, unsigned c){
    float lo = __uint_as_float(a<<16) + __uint_as_float(b<<16) + __uint_as_float(c<<16);
    float hi = __uint_as_float(a&0xFFFF0000u) + __uint_as_float(b&0xFFFF0000u)
             + __uint_as_float(c&0xFFFF0000u);
    return f2bf1(lo) | (f2bf1(hi)<<16);
}

// ---------------------------------------------------------------------------
// prep_tbl: fp32 emb table -> bf16 copy.
// ---------------------------------------------------------------------------
__global__ __launch_bounds__(256) void prep_tbl(
    const float* __restrict__ tbl, uint2* __restrict__ tblh)
{
    int idx = blockIdx.x*256 + threadIdx.x;
    if (idx < (V_*E_)/4) {
        float4 v = ((const float4*)tbl)[idx];
        uint2 o;
        o.x = f2bf1(v.x) | (f2bf1(v.y)<<16);
        o.y = f2bf1(v.z) | (f2bf1(v.w)<<16);
        tblh[idx] = o;
    }
}

// ---------------------------------------------------------------------------
// prep_w: W1/W2 bf16 MFMA B-fragment images.
// ---------------------------------------------------------------------------
__global__ __launch_bounds__(64) void prep_w(
    const float* __restrict__ W1, const float* __restrict__ W2,
    uint4* __restrict__ W1f, uint4* __restrict__ W2f)
{
    const int idx = blockIdx.x*64 + threadIdx.x;
    if (idx < 7*4*64) {
        int lane = idx & 63, kt = (idx>>6)&3, nt = idx>>8;
        int n = nt*16 + (lane&15);
        int kb = kt*32 + (lane>>4)*8;
        unsigned wv[4];
        #pragma unroll
        for (int p = 0; p < 4; ++p) {
            float v0 = (n < H_) ? W1[(kb+2*p  )*H_ + n] : 0.f;
            float v1 = (n < H_) ? W1[(kb+2*p+1)*H_ + n] : 0.f;
            wv[p] = f2bf1(v0) | (f2bf1(v1) << 16);
        }
        W1f[idx] = make_uint4(wv[0],wv[1],wv[2],wv[3]);
    } else {
        int id2 = idx - 7*4*64;
        int lane = id2 & 63, kt = (id2>>6)&3, nt = id2>>8;
        int n = nt*16 + (lane&15);
        int kb = kt*32 + (lane>>4)*8;
        unsigned wv[4];
        #pragma unroll
        for (int p = 0; p < 4; ++p) {
            int k0 = kb+2*p, k1 = kb+2*p+1;
            float v0 = (k0 < H_) ? W2[k0*T_ + n] : 0.f;
            float v1 = (k1 < H_) ? W2[k1*T_ + n] : 0.f;
            wv[p] = f2bf1(v0) | (f2bf1(v1) << 16);
        }
        W2f[id2] = make_uint4(wv[0],wv[1],wv[2],wv[3]);
    }
}

// ---------------------------------------------------------------------------
// MLP (unchanged — control).
// ---------------------------------------------------------------------------
__global__ __launch_bounds__(256, 6) void mlp_kernel(
    const int* __restrict__ inputs, const unsigned short* __restrict__ tblh,
    const float* __restrict__ b1, const float* __restrict__ b2,
    const uint4* __restrict__ W1f, const uint4* __restrict__ W2f,
    unsigned short* __restrict__ em)
{
    __shared__ uint4 sA2[1024];

    const int tid  = threadIdx.x;
    const int lane = tid & 63;
    const int w    = tid >> 6;
    const int col  = lane & 15;
    const int hi   = lane >> 4;
    const int rowin = hi * 4;

    const int rg = blockIdx.x*64 + w*16 + col;
    const int i0 = inputs[rg*3+0], i1 = inputs[rg*3+1], i2 = inputs[rg*3+2];
    const unsigned short* tr0 = tblh + (size_t)i0*E_;
    const unsigned short* tr1 = tblh + (size_t)i1*E_;
    const unsigned short* tr2 = tblh + (size_t)i2*E_;

    U16x4 a[4];
    #pragma unroll
    for (int kt = 0; kt < 4; ++kt) {
        int off = kt*32 + hi*8;
        uint4 u0 = *(const uint4*)(tr0 + off);
        uint4 u1 = *(const uint4*)(tr1 + off);
        uint4 u2 = *(const uint4*)(tr2 + off);
        a[kt].u = make_uint4(addpack3(u0.x,u1.x,u2.x), addpack3(u0.y,u1.y,u2.y),
                             addpack3(u0.z,u1.z,u2.z), addpack3(u0.w,u1.w,u2.w));
    }

    f32x4 acc1[7];
    #pragma unroll
    for (int nt = 0; nt < 7; ++nt) {
        int n = nt*16 + col;
        float bv = (n < H_) ? b1[n] : 0.f;
        f32x4 c; c[0]=bv; c[1]=bv; c[2]=bv; c[3]=bv;
        #pragma unroll
        for (int k = 0; k < 4; ++k) {
            U16x4 bfr; bfr.u = W1f[(nt*4+k)*64 + lane];
            c = __builtin_amdgcn_mfma_f32_16x16x32_bf16(a[k].s, bfr.s, c, 0,0,0);
        }
        acc1[nt] = c;
    }
    #pragma unroll
    for (int nt = 0; nt < 7; ++nt)
        #pragma unroll
        for (int rr = 0; rr < 4; ++rr) {
            float x = acc1[nt][rr];
            acc1[nt][rr] = 1.f - 2.f/(__expf(2.f*x)+1.f);
        }

    if (lane >= 32) sA2[(w*4+3)*64 + lane] = make_uint4(0,0,0,0);
    unsigned short* A2h = (unsigned short*)sA2;
    #pragma unroll
    for (int nt = 0; nt < 7; ++nt)
        #pragma unroll
        for (int rr = 0; rr < 4; ++rr) {
            int k2 = nt*16 + col;
            int kt2 = k2 >> 5, g2 = (k2>>3)&3, i2v = k2&7;
            int u4idx = (w*4 + kt2)*64 + g2*16 + (rowin + rr);
            A2h[u4idx*8 + i2v] = (unsigned short)f2bf1(acc1[nt][rr]);
        }
    __builtin_amdgcn_wave_barrier();

    U16x4 a2[4];
    #pragma unroll
    for (int k = 0; k < 4; ++k) a2[k].u = sA2[(w*4+k)*64 + lane];
    __builtin_amdgcn_wave_barrier();

    unsigned short* tbuf = (unsigned short*)(sA2 + (size_t)w*256);
    #pragma unroll
    for (int nt2 = 0; nt2 < 4; ++nt2) {
        float bv = b2[nt2*16 + col];
        f32x4 c; c[0]=bv; c[1]=bv; c[2]=bv; c[3]=bv;
        #pragma unroll
        for (int k = 0; k < 4; ++k) {
            U16x4 bfr; bfr.u = W2f[(nt2*4+k)*64 + lane];
            c = __builtin_amdgcn_mfma_f32_16x16x32_bf16(a2[k].s, bfr.s, c, 0,0,0);
        }
        #pragma unroll
        for (int rr = 0; rr < 4; ++rr)
            tbuf[(rowin+rr)*72 + nt2*16 + col] = (unsigned short)f2bf1(c[rr]);
    }
    __builtin_amdgcn_wave_barrier();

    {
        const int rl = lane >> 2;
        const int ch = (lane & 3) * 2;
        const uint4* t4 = (const uint4*)tbuf;
        uint4 u0 = t4[rl*9 + ch];
        uint4 u1 = t4[rl*9 + ch + 1];
        size_t rowg = (size_t)(blockIdx.x*64 + w*16 + rl);
        uint4* dst = (uint4*)(em + rowg*T_);
        dst[ch]   = u0;
        dst[ch+1] = u1;
    }
}

// ---------------------------------------------------------------------------
// CRF bidirectional scan, TWO WAVES PER BLOCK (r12 repartitioned):
//   wave 0: fwd  a <- mask ? (E^T a) o e_t : a, t = 0..255 (bit0 cleared)
//   wave 1: bwd  b <- mask ? E (e_t o b) : b,   t = 511 down to 256
// Each wave runs the proven r4 768-cyc/step loop on its OWN SIMD — true
// concurrency (r12 put both chains in one wave: DS ops serialized, 1530/step).
// Merge: logZ = lsF + lsB + log(sum_j aF_j * aB_j). Numerator split by half.
// ---------------------------------------------------------------------------
__global__ __launch_bounds__(128) void crf_kernel(
    const int* __restrict__ inputs, const int* __restrict__ tags,
    const unsigned short* __restrict__ em, const float* __restrict__ start_trans,
    const float* __restrict__ end_trans, const float* __restrict__ trans,
    float* __restrict__ out)
{
    __shared__ __align__(16) unsigned short semA[2][512];
    __shared__ __align__(16) unsigned short semBv[2][512];
    __shared__ __align__(16) float pbufA[T_];
    __shared__ __align__(16) float pbufB[T_];
    __shared__ float fnum[2];
    __shared__ int   icnt[2];
    __shared__ float lsB_sh;

    const int b   = blockIdx.x;
    const int tid = threadIdx.x;
    const int w   = tid >> 6;            // 0 = fwd wave, 1 = bwd wave
    const int j   = tid & 63;
    const unsigned short* em_b = em + (size_t)b*S_*T_;
    const int* tags_b = tags + b*S_;
    const int* in_b = inputs + (size_t)b*S_*3;

    unsigned short (*sem)[512] = w ? semBv : semA;
    float* pbuf = w ? pbufB : pbufA;

    // ---- mask ballots + numerator partial for THIS wave's half ----
    unsigned long long mball[4];
    float partial = 0.f;
    #pragma unroll
    for (int g4 = 0; g4 < 4; ++g4) {
        int t = (w*4 + g4)*64 + j;
        int a0 = in_b[t*3+0], a1 = in_b[t*3+1], a2 = in_b[t*3+2];
        bool mk = ((a0 | a1 | a2) != 0);
        mball[g4] = __ballot(mk);
        if (t >= 1 && mk) {
            int tp = tags_b[t-1], tc = tags_b[t];
            partial += trans[tp*T_ + tc] + bf2f(em_b[(size_t)t*T_ + tc]);
        }
    }
    int cnt = 0;
    #pragma unroll
    for (int g4 = 0; g4 < 4; ++g4) cnt += __popcll(mball[g4]);
    if (w == 0) mball[0] &= ~1ull;       // t=0 is not a scan step
    #pragma unroll
    for (int off = 32; off >= 1; off >>= 1) partial += __shfl_xor(partial, off, 64);
    if (w == 0) {
        const int tag0 = tags_b[0];
        partial += start_trans[tag0] + bf2f(em_b[tag0]);
    }
    if (j == 0) { fnum[w] = partial; icnt[w] = cnt; }

    // ---- E pairs: fwd = E column j; bwd = E row j ----
    f32x2 E2[32];
    #pragma unroll
    for (int i = 0; i < 32; ++i) {
        f32x2 e;
        if (w == 0) { e.x = __expf(trans[(2*i)*T_ + j]); e.y = __expf(trans[(2*i+1)*T_ + j]); }
        else        { e.x = __expf(trans[j*T_ + 2*i]);   e.y = __expf(trans[j*T_ + 2*i+1]); }
        E2[i] = e;
    }

    // ---- init ----
    float a, ls;
    if (w == 0) {
        float x0v = start_trans[j] + bf2f(em_b[j]);
        ls = rfl_f(x0v);
        a  = __expf(x0v - ls);
    } else {
        a  = __expf(end_trans[j]);
        ls = 0.f;
    }

    // ---- group staging (this wave's 32 groups; bwd descending) ----
    const uint4* em4 = (const uint4*)em_b;
    auto agof = [&](int k){ return w ? (63 - k) : k; };
    uint4 gbuf = em4[agof(0)*64 + j];
    ((uint4*)sem[0])[j] = gbuf;
    __builtin_amdgcn_wave_barrier();
    float eg[8];
    #pragma unroll
    for (int s = 0; s < 8; ++s)
        eg[s] = __expf(bf2f(sem[0][(w ? (7-s) : s)*T_ + j]));
    gbuf = em4[agof(1)*64 + j];

    auto matv = [&](const float4* p4) -> float {
        f32x2 ac0={0.f,0.f}, ac1={0.f,0.f}, ac2={0.f,0.f}, ac3={0.f,0.f};
        #pragma unroll
        for (int q = 0; q < 4; ++q) {
            float4 A0 = p4[4*q+0], A1 = p4[4*q+1], A2v = p4[4*q+2], A3 = p4[4*q+3];
            f32x2 p0; p0.x=A0.x; p0.y=A0.y;  f32x2 p1; p1.x=A0.z; p1.y=A0.w;
            f32x2 p2; p2.x=A1.x; p2.y=A1.y;  f32x2 p3; p3.x=A1.z; p3.y=A1.w;
            f32x2 p4v; p4v.x=A2v.x;p4v.y=A2v.y; f32x2 p5; p5.x=A2v.z;p5.y=A2v.w;
            f32x2 p6; p6.x=A3.x; p6.y=A3.y;  f32x2 p7; p7.x=A3.z; p7.y=A3.w;
            ac0 = p0 *E2[8*q+0] + ac0;  ac1 = p1*E2[8*q+1] + ac1;
            ac2 = p2 *E2[8*q+2] + ac2;  ac3 = p3*E2[8*q+3] + ac3;
            ac0 = p4v*E2[8*q+4] + ac0;  ac1 = p5*E2[8*q+5] + ac1;
            ac2 = p6 *E2[8*q+6] + ac2;  ac3 = p7*E2[8*q+7] + ac3;
        }
        f32x2 st = (ac0+ac1)+(ac2+ac3);
        return st.x + st.y;
    };

    for (int k = 0; k < 32; ++k) {
        unsigned short raw16[8];
        if (k < 31) {
            ((uint4*)sem[(k+1)&1])[j] = gbuf;
            __builtin_amdgcn_wave_barrier();
            #pragma unroll
            for (int s = 0; s < 8; ++s)
                raw16[s] = sem[(k+1)&1][(w ? (7-s) : s)*T_ + j];
            if (k < 30) gbuf = em4[agof(k+2)*64 + j];
        }
        const int ag = agof(k);
        const unsigned mg = (unsigned)((mball[(ag>>3) - w*4] >> ((ag&7)*8)) & 0xFFull);

        #pragma unroll
        for (int s = 0; s < 8; ++s) {
            pbuf[j] = (w == 0) ? a : (eg[s] * a);   // bwd: e_t o b pre-scaled
            __builtin_amdgcn_wave_barrier();
            float sc   = rfl_f(a);
            float sinv = __builtin_amdgcn_rcpf(sc);
            float logs = __logf(sc);
            float keep = a * sinv;
            float dmul = (w == 0) ? (eg[s] * sinv) : sinv;

            float dot = matv((const float4*)pbuf);

            float cand = dot * dmul;
            const int bit = (w == 0) ? s : (7 - s);
            a = ((mg >> bit) & 1u) ? cand : keep;
            ls += logs;
            __builtin_amdgcn_wave_barrier();
        }
        if (k < 31) {
            #pragma unroll
            for (int s = 0; s < 8; ++s) eg[s] = __expf(bf2f(raw16[s]));
        }
    }

    // ---- merge ----
    if (w == 1) {
        pbufB[j] = a;                    // publish aB
        if (j == 0) lsB_sh = ls;
    }
    __syncthreads();
    if (w == 0) {
        float x = a * pbufB[j];
        #pragma unroll
        for (int off = 32; off >= 1; off >>= 1) x += __shfl_xor(x, off, 64);
        int mcount = icnt[0] + icnt[1];
        int se = mcount - 1; if (se < 0) se = 0;
        const int last_tag = tags_b[se];
        float numer = fnum[0] + fnum[1] + end_trans[last_tag];
        if (j == 0) out[b] = ls + lsB_sh + __logf(x) - numer;
    }
}

// ---------------------------------------------------------------------------
extern "C" void kernel_launch(void* const* d_in, const int* in_sizes, int n_in,
                              void* d_out, int out_size, void* d_ws, size_t ws_size,
                              hipStream_t stream) {
    const int*   inputs      = (const int*)  d_in[0];
    const int*   tags        = (const int*)  d_in[1];
    const float* emb_table   = (const float*)d_in[2];
    const float* W1          = (const float*)d_in[3];
    const float* b1          = (const float*)d_in[4];
    const float* W2          = (const float*)d_in[5];
    const float* b2          = (const float*)d_in[6];
    const float* start_trans = (const float*)d_in[7];
    const float* end_trans   = (const float*)d_in[8];
    const float* transitions = (const float*)d_in[9];
    float* out = (float*)d_out;

    // ws: em bf16 (32 MiB) | W1f 28KB | W2f 16KB | tblh bf16 (25.6 MB)
    unsigned short* em = (unsigned short*)d_ws;
    uint4* W1f = (uint4*)((char*)d_ws + (size_t)BS_*T_*2);
    uint4* W2f = W1f + 7*4*64;
    unsigned short* tblh = (unsigned short*)((char*)d_ws + (size_t)BS_*T_*2 + 28672 + 16384);

    prep_tbl<<<dim3((V_*E_/4 + 255)/256), dim3(256), 0, stream>>>(emb_table, (uint2*)tblh);
    prep_w<<<dim3((7*4*64 + 4*4*64)/64), dim3(64), 0, stream>>>(W1, W2, W1f, W2f);
    mlp_kernel<<<dim3(BS_/64), dim3(256), 0, stream>>>(
        inputs, tblh, b1, b2, W1f, W2f, em);
    crf_kernel<<<dim3(B_), dim3(128), 0, stream>>>(
        inputs, tags, em, start_trans, end_trans, transitions, out);
}

// Round 14
// 289.341 us; speedup vs baseline: 1.2091x; 1.2091x over previous
//
#include <hip/hip_runtime.h>

#define B_ 512
#define S_ 512
#define E_ 128
#define H_ 100
#define T_ 64
#define V_ 100000
#define BS_ (B_*S_)

typedef __attribute__((ext_vector_type(8))) short bf16x8;
typedef __attribute__((ext_vector_type(4))) float f32x4;
typedef _Float16 h2 __attribute__((ext_vector_type(2)));
union U16x4 { uint4 u; bf16x8 s; };

__device__ __forceinline__ unsigned f2bf1(float x){
    unsigned u = __float_as_uint(x);
    return (u + 0x7FFFu + ((u>>16)&1u)) >> 16;
}
__device__ __forceinline__ float bf2f(unsigned short h){
    return __uint_as_float(((unsigned)h)<<16);
}
__device__ __forceinline__ float rfl_f(float x){
    return __uint_as_float(__builtin_amdgcn_readfirstlane(__float_as_uint(x)));
}
__device__ __forceinline__ unsigned addpack3(unsigned a, unsigned b, unsigned c){
    float lo = __uint_as_float(a<<16) + __uint_as_float(b<<16) + __uint_as_float(c<<16);
    float hi = __uint_as_float(a&0xFFFF0000u) + __uint_as_float(b&0xFFFF0000u)
             + __uint_as_float(c&0xFFFF0000u);
    return f2bf1(lo) | (f2bf1(hi)<<16);
}
// half2-pair dot with fp32 accumulate (v_dot2_f32_f16); fallback = cvt+fma
__device__ __forceinline__ float fdot2h(unsigned u, h2 e, float c){
    h2 p; __builtin_memcpy(&p, &u, 4);
#if __has_builtin(__builtin_amdgcn_fdot2)
    return __builtin_amdgcn_fdot2(p, e, c, false);
#else
    return fmaf((float)p.x, (float)e.x, fmaf((float)p.y, (float)e.y, c));
#endif
}

// ---------------------------------------------------------------------------
// prep_tbl: fp32 emb table -> bf16 copy.
// ---------------------------------------------------------------------------
__global__ __launch_bounds__(256) void prep_tbl(
    const float* __restrict__ tbl, uint2* __restrict__ tblh)
{
    int idx = blockIdx.x*256 + threadIdx.x;
    if (idx < (V_*E_)/4) {
        float4 v = ((const float4*)tbl)[idx];
        uint2 o;
        o.x = f2bf1(v.x) | (f2bf1(v.y)<<16);
        o.y = f2bf1(v.z) | (f2bf1(v.w)<<16);
        tblh[idx] = o;
    }
}

// ---------------------------------------------------------------------------
// prep_w: W1/W2 bf16 MFMA B-fragment images.
// ---------------------------------------------------------------------------
__global__ __launch_bounds__(64) void prep_w(
    const float* __restrict__ W1, const float* __restrict__ W2,
    uint4* __restrict__ W1f, uint4* __restrict__ W2f)
{
    const int idx = blockIdx.x*64 + threadIdx.x;
    if (idx < 7*4*64) {
        int lane = idx & 63, kt = (idx>>6)&3, nt = idx>>8;
        int n = nt*16 + (lane&15);
        int kb = kt*32 + (lane>>4)*8;
        unsigned wv[4];
        #pragma unroll
        for (int p = 0; p < 4; ++p) {
            float v0 = (n < H_) ? W1[(kb+2*p  )*H_ + n] : 0.f;
            float v1 = (n < H_) ? W1[(kb+2*p+1)*H_ + n] : 0.f;
            wv[p] = f2bf1(v0) | (f2bf1(v1) << 16);
        }
        W1f[idx] = make_uint4(wv[0],wv[1],wv[2],wv[3]);
    } else {
        int id2 = idx - 7*4*64;
        int lane = id2 & 63, kt = (id2>>6)&3, nt = id2>>8;
        int n = nt*16 + (lane&15);
        int kb = kt*32 + (lane>>4)*8;
        unsigned wv[4];
        #pragma unroll
        for (int p = 0; p < 4; ++p) {
            int k0 = kb+2*p, k1 = kb+2*p+1;
            float v0 = (k0 < H_) ? W2[k0*T_ + n] : 0.f;
            float v1 = (k1 < H_) ? W2[k1*T_ + n] : 0.f;
            wv[p] = f2bf1(v0) | (f2bf1(v1) << 16);
        }
        W2f[id2] = make_uint4(wv[0],wv[1],wv[2],wv[3]);
    }
}

// ---------------------------------------------------------------------------
// MLP (unchanged — control).
// ---------------------------------------------------------------------------
__global__ __launch_bounds__(256, 6) void mlp_kernel(
    const int* __restrict__ inputs, const unsigned short* __restrict__ tblh,
    const float* __restrict__ b1, const float* __restrict__ b2,
    const uint4* __restrict__ W1f, const uint4* __restrict__ W2f,
    unsigned short* __restrict__ em)
{
    __shared__ uint4 sA2[1024];

    const int tid  = threadIdx.x;
    const int lane = tid & 63;
    const int w    = tid >> 6;
    const int col  = lane & 15;
    const int hi   = lane >> 4;
    const int rowin = hi * 4;

    const int rg = blockIdx.x*64 + w*16 + col;
    const int i0 = inputs[rg*3+0], i1 = inputs[rg*3+1], i2 = inputs[rg*3+2];
    const unsigned short* tr0 = tblh + (size_t)i0*E_;
    const unsigned short* tr1 = tblh + (size_t)i1*E_;
    const unsigned short* tr2 = tblh + (size_t)i2*E_;

    U16x4 a[4];
    #pragma unroll
    for (int kt = 0; kt < 4; ++kt) {
        int off = kt*32 + hi*8;
        uint4 u0 = *(const uint4*)(tr0 + off);
        uint4 u1 = *(const uint4*)(tr1 + off);
        uint4 u2 = *(const uint4*)(tr2 + off);
        a[kt].u = make_uint4(addpack3(u0.x,u1.x,u2.x), addpack3(u0.y,u1.y,u2.y),
                             addpack3(u0.z,u1.z,u2.z), addpack3(u0.w,u1.w,u2.w));
    }

    f32x4 acc1[7];
    #pragma unroll
    for (int nt = 0; nt < 7; ++nt) {
        int n = nt*16 + col;
        float bv = (n < H_) ? b1[n] : 0.f;
        f32x4 c; c[0]=bv; c[1]=bv; c[2]=bv; c[3]=bv;
        #pragma unroll
        for (int k = 0; k < 4; ++k) {
            U16x4 bfr; bfr.u = W1f[(nt*4+k)*64 + lane];
            c = __builtin_amdgcn_mfma_f32_16x16x32_bf16(a[k].s, bfr.s, c, 0,0,0);
        }
        acc1[nt] = c;
    }
    #pragma unroll
    for (int nt = 0; nt < 7; ++nt)
        #pragma unroll
        for (int rr = 0; rr < 4; ++rr) {
            float x = acc1[nt][rr];
            acc1[nt][rr] = 1.f - 2.f/(__expf(2.f*x)+1.f);
        }

    if (lane >= 32) sA2[(w*4+3)*64 + lane] = make_uint4(0,0,0,0);
    unsigned short* A2h = (unsigned short*)sA2;
    #pragma unroll
    for (int nt = 0; nt < 7; ++nt)
        #pragma unroll
        for (int rr = 0; rr < 4; ++rr) {
            int k2 = nt*16 + col;
            int kt2 = k2 >> 5, g2 = (k2>>3)&3, i2v = k2&7;
            int u4idx = (w*4 + kt2)*64 + g2*16 + (rowin + rr);
            A2h[u4idx*8 + i2v] = (unsigned short)f2bf1(acc1[nt][rr]);
        }
    __builtin_amdgcn_wave_barrier();

    U16x4 a2[4];
    #pragma unroll
    for (int k = 0; k < 4; ++k) a2[k].u = sA2[(w*4+k)*64 + lane];
    __builtin_amdgcn_wave_barrier();

    unsigned short* tbuf = (unsigned short*)(sA2 + (size_t)w*256);
    #pragma unroll
    for (int nt2 = 0; nt2 < 4; ++nt2) {
        float bv = b2[nt2*16 + col];
        f32x4 c; c[0]=bv; c[1]=bv; c[2]=bv; c[3]=bv;
        #pragma unroll
        for (int k = 0; k < 4; ++k) {
            U16x4 bfr; bfr.u = W2f[(nt2*4+k)*64 + lane];
            c = __builtin_amdgcn_mfma_f32_16x16x32_bf16(a2[k].s, bfr.s, c, 0,0,0);
        }
        #pragma unroll
        for (int rr = 0; rr < 4; ++rr)
            tbuf[(rowin+rr)*72 + nt2*16 + col] = (unsigned short)f2bf1(c[rr]);
    }
    __builtin_amdgcn_wave_barrier();

    {
        const int rl = lane >> 2;
        const int ch = (lane & 3) * 2;
        const uint4* t4 = (const uint4*)tbuf;
        uint4 u0 = t4[rl*9 + ch];
        uint4 u1 = t4[rl*9 + ch + 1];
        size_t rowg = (size_t)(blockIdx.x*64 + w*16 + rl);
        uint4* dst = (uint4*)(em + rowg*T_);
        dst[ch]   = u0;
        dst[ch+1] = u1;
    }
}

// ---------------------------------------------------------------------------
// CRF bidirectional scan, two waves per block (r13 structure), with the
// broadcast in FP16: write ds_write_b16, read 8x ds_read_b128 (was 16),
// fold with v_dot2_f32_f16 (fp32 accumulate). Halves the per-step LDS bytes
// and DS op count — r13 showed 4 scan-waves/CU saturate the LDS pipe
// (16.4 KB/step/wave @ ~85 B/cyc -> 1847 cyc/step). Values centered by 1/64
// before fp16 cast (worst-case spread e^±11 -> max 1.9e4 < 65504), exact
// compensation x64 folded into fp32 dmul.
// ---------------------------------------------------------------------------
__global__ __launch_bounds__(128) void crf_kernel(
    const int* __restrict__ inputs, const int* __restrict__ tags,
    const unsigned short* __restrict__ em, const float* __restrict__ start_trans,
    const float* __restrict__ end_trans, const float* __restrict__ trans,
    float* __restrict__ out)
{
    __shared__ __align__(16) unsigned short semA[2][512];
    __shared__ __align__(16) unsigned short semBv[2][512];
    __shared__ __align__(16) _Float16 pbufHA[T_];
    __shared__ __align__(16) _Float16 pbufHB[T_];
    __shared__ float pubB[T_];
    __shared__ float fnum[2];
    __shared__ int   icnt[2];
    __shared__ float lsB_sh;

    const int b   = blockIdx.x;
    const int tid = threadIdx.x;
    const int w   = tid >> 6;            // 0 = fwd wave, 1 = bwd wave
    const int j   = tid & 63;
    const unsigned short* em_b = em + (size_t)b*S_*T_;
    const int* tags_b = tags + b*S_;
    const int* in_b = inputs + (size_t)b*S_*3;

    unsigned short (*sem)[512] = w ? semBv : semA;
    _Float16* pbufH = w ? pbufHB : pbufHA;

    // ---- mask ballots + numerator partial for THIS wave's half ----
    unsigned long long mball[4];
    float partial = 0.f;
    #pragma unroll
    for (int g4 = 0; g4 < 4; ++g4) {
        int t = (w*4 + g4)*64 + j;
        int a0 = in_b[t*3+0], a1 = in_b[t*3+1], a2 = in_b[t*3+2];
        bool mk = ((a0 | a1 | a2) != 0);
        mball[g4] = __ballot(mk);
        if (t >= 1 && mk) {
            int tp = tags_b[t-1], tc = tags_b[t];
            partial += trans[tp*T_ + tc] + bf2f(em_b[(size_t)t*T_ + tc]);
        }
    }
    int cnt = 0;
    #pragma unroll
    for (int g4 = 0; g4 < 4; ++g4) cnt += __popcll(mball[g4]);
    if (w == 0) mball[0] &= ~1ull;       // t=0 is not a scan step
    #pragma unroll
    for (int off = 32; off >= 1; off >>= 1) partial += __shfl_xor(partial, off, 64);
    if (w == 0) {
        const int tag0 = tags_b[0];
        partial += start_trans[tag0] + bf2f(em_b[tag0]);
    }
    if (j == 0) { fnum[w] = partial; icnt[w] = cnt; }

    // ---- E pairs in fp16: fwd = E column j; bwd = E row j ----
    h2 E2[32];
    #pragma unroll
    for (int i = 0; i < 32; ++i) {
        h2 e;
        if (w == 0) { e.x = (_Float16)__expf(trans[(2*i)*T_ + j]);
                      e.y = (_Float16)__expf(trans[(2*i+1)*T_ + j]); }
        else        { e.x = (_Float16)__expf(trans[j*T_ + 2*i]);
                      e.y = (_Float16)__expf(trans[j*T_ + 2*i+1]); }
        E2[i] = e;
    }

    // ---- init ----
    float a, ls;
    if (w == 0) {
        float x0v = start_trans[j] + bf2f(em_b[j]);
        ls = rfl_f(x0v);
        a  = __expf(x0v - ls);
    } else {
        a  = __expf(end_trans[j]);
        ls = 0.f;
    }

    // ---- group staging (this wave's 32 groups; bwd descending) ----
    const uint4* em4 = (const uint4*)em_b;
    auto agof = [&](int k){ return w ? (63 - k) : k; };
    uint4 gbuf = em4[agof(0)*64 + j];
    ((uint4*)sem[0])[j] = gbuf;
    __builtin_amdgcn_wave_barrier();
    float eg[8];
    #pragma unroll
    for (int s = 0; s < 8; ++s)
        eg[s] = __expf(bf2f(sem[0][(w ? (7-s) : s)*T_ + j]));
    gbuf = em4[agof(1)*64 + j];

    for (int k = 0; k < 32; ++k) {
        unsigned short raw16[8];
        if (k < 31) {
            ((uint4*)sem[(k+1)&1])[j] = gbuf;
            __builtin_amdgcn_wave_barrier();
            #pragma unroll
            for (int s = 0; s < 8; ++s)
                raw16[s] = sem[(k+1)&1][(w ? (7-s) : s)*T_ + j];
            if (k < 30) gbuf = em4[agof(k+2)*64 + j];
        }
        const int ag = agof(k);
        const unsigned mg = (unsigned)((mball[(ag>>3) - w*4] >> ((ag&7)*8)) & 0xFFull);

        #pragma unroll
        for (int s = 0; s < 8; ++s) {
            float wv = (w == 0) ? a : (eg[s] * a);       // bwd: e_t o b pre-mul
            pbufH[j] = (_Float16)(wv * 0.015625f);       // 1/64 centering
            __builtin_amdgcn_wave_barrier();
            // off-chain scale prep (overlaps LDS round-trip)
            float sc   = rfl_f(a);
            float sinv = __builtin_amdgcn_rcpf(sc);
            float logs = __logf(sc);
            float keep = a * sinv;
            float dmul = ((w == 0) ? (eg[s] * sinv) : sinv) * 64.0f;

            const uint4* ph = (const uint4*)pbufH;
            float ac0=0.f, ac1=0.f, ac2=0.f, ac3=0.f;
            #pragma unroll
            for (int q = 0; q < 8; ++q) {
                uint4 U = ph[q];
                ac0 = fdot2h(U.x, E2[4*q+0], ac0);
                ac1 = fdot2h(U.y, E2[4*q+1], ac1);
                ac2 = fdot2h(U.z, E2[4*q+2], ac2);
                ac3 = fdot2h(U.w, E2[4*q+3], ac3);
            }
            float dot = (ac0+ac1)+(ac2+ac3);
            float cand = dot * dmul;
            const int bit = (w == 0) ? s : (7 - s);
            a = ((mg >> bit) & 1u) ? cand : keep;
            ls += logs;
            __builtin_amdgcn_wave_barrier();
        }
        if (k < 31) {
            #pragma unroll
            for (int s = 0; s < 8; ++s) eg[s] = __expf(bf2f(raw16[s]));
        }
    }

    // ---- merge: logZ = lsF + lsB + log(sum_j aF_j * aB_j) ----
    if (w == 1) {
        pubB[j] = a;
        if (j == 0) lsB_sh = ls;
    }
    __syncthreads();
    if (w == 0) {
        float x = a * pubB[j];
        #pragma unroll
        for (int off = 32; off >= 1; off >>= 1) x += __shfl_xor(x, off, 64);
        int mcount = icnt[0] + icnt[1];
        int se = mcount - 1; if (se < 0) se = 0;
        const int last_tag = tags_b[se];
        float numer = fnum[0] + fnum[1] + end_trans[last_tag];
        if (j == 0) out[b] = ls + lsB_sh + __logf(x) - numer;
    }
}

// ---------------------------------------------------------------------------
extern "C" void kernel_launch(void* const* d_in, const int* in_sizes, int n_in,
                              void* d_out, int out_size, void* d_ws, size_t ws_size,
                              hipStream_t stream) {
    const int*   inputs      = (const int*)  d_in[0];
    const int*   tags        = (const int*)  d_in[1];
    const float* emb_table   = (const float*)d_in[2];
    const float* W1          = (const float*)d_in[3];
    const float* b1          = (const float*)d_in[4];
    const float* W2          = (const float*)d_in[5];
    const float* b2          = (const float*)d_in[6];
    const float* start_trans = (const float*)d_in[7];
    const float* end_trans   = (const float*)d_in[8];
    const float* transitions = (const float*)d_in[9];
    float* out = (float*)d_out;

    // ws: em bf16 (32 MiB) | W1f 28KB | W2f 16KB | tblh bf16 (25.6 MB)
    unsigned short* em = (unsigned short*)d_ws;
    uint4* W1f = (uint4*)((char*)d_ws + (size_t)BS_*T_*2);
    uint4* W2f = W1f + 7*4*64;
    unsigned short* tblh = (unsigned short*)((char*)d_ws + (size_t)BS_*T_*2 + 28672 + 16384);

    prep_tbl<<<dim3((V_*E_/4 + 255)/256), dim3(256), 0, stream>>>(emb_table, (uint2*)tblh);
    prep_w<<<dim3((7*4*64 + 4*4*64)/64), dim3(64), 0, stream>>>(W1, W2, W1f, W2f);
    mlp_kernel<<<dim3(BS_/64), dim3(256), 0, stream>>>(
        inputs, tblh, b1, b2, W1f, W2f, em);
    crf_kernel<<<dim3(B_), dim3(128), 0, stream>>>(
        inputs, tags, em, start_trans, end_trans, transitions, out);
}

// Round 15
// 239.574 us; speedup vs baseline: 1.4603x; 1.2077x over previous
//
#include <hip/hip_runtime.h>

#define B_ 512
#define S_ 512
#define E_ 128
#define H_ 100
#define T_ 64
#define V_ 100000
#define BS_ (B_*S_)

typedef __attribute__((ext_vector_type(8))) short bf16x8;
typedef __attribute__((ext_vector_type(4))) float f32x4;
typedef _Float16 h2 __attribute__((ext_vector_type(2)));
union U16x4 { uint4 u; bf16x8 s; };

__device__ __forceinline__ unsigned f2bf1(float x){
    unsigned u = __float_as_uint(x);
    return (u + 0x7FFFu + ((u>>16)&1u)) >> 16;
}
__device__ __forceinline__ float bf2f(unsigned short h){
    return __uint_as_float(((unsigned)h)<<16);
}
__device__ __forceinline__ float rfl_f(float x){
    return __uint_as_float(__builtin_amdgcn_readfirstlane(__float_as_uint(x)));
}
__device__ __forceinline__ unsigned addpack3(unsigned a, unsigned b, unsigned c){
    float lo = __uint_as_float(a<<16) + __uint_as_float(b<<16) + __uint_as_float(c<<16);
    float hi = __uint_as_float(a&0xFFFF0000u) + __uint_as_float(b&0xFFFF0000u)
             + __uint_as_float(c&0xFFFF0000u);
    return f2bf1(lo) | (f2bf1(hi)<<16);
}
__device__ __forceinline__ float fdot2h(unsigned u, h2 e, float c){
    h2 p; __builtin_memcpy(&p, &u, 4);
#if __has_builtin(__builtin_amdgcn_fdot2)
    return __builtin_amdgcn_fdot2(p, e, c, false);
#else
    return fmaf((float)p.x, (float)e.x, fmaf((float)p.y, (float)e.y, c));
#endif
}

// ---------------------------------------------------------------------------
// prep_tbl: fp32 emb table -> bf16 copy.
// ---------------------------------------------------------------------------
__global__ __launch_bounds__(256) void prep_tbl(
    const float* __restrict__ tbl, uint2* __restrict__ tblh)
{
    int idx = blockIdx.x*256 + threadIdx.x;
    if (idx < (V_*E_)/4) {
        float4 v = ((const float4*)tbl)[idx];
        uint2 o;
        o.x = f2bf1(v.x) | (f2bf1(v.y)<<16);
        o.y = f2bf1(v.z) | (f2bf1(v.w)<<16);
        tblh[idx] = o;
    }
}

// ---------------------------------------------------------------------------
// prep_w: W1/W2 bf16 MFMA B-fragment images.
// ---------------------------------------------------------------------------
__global__ __launch_bounds__(64) void prep_w(
    const float* __restrict__ W1, const float* __restrict__ W2,
    uint4* __restrict__ W1f, uint4* __restrict__ W2f)
{
    const int idx = blockIdx.x*64 + threadIdx.x;
    if (idx < 7*4*64) {
        int lane = idx & 63, kt = (idx>>6)&3, nt = idx>>8;
        int n = nt*16 + (lane&15);
        int kb = kt*32 + (lane>>4)*8;
        unsigned wv[4];
        #pragma unroll
        for (int p = 0; p < 4; ++p) {
            float v0 = (n < H_) ? W1[(kb+2*p  )*H_ + n] : 0.f;
            float v1 = (n < H_) ? W1[(kb+2*p+1)*H_ + n] : 0.f;
            wv[p] = f2bf1(v0) | (f2bf1(v1) << 16);
        }
        W1f[idx] = make_uint4(wv[0],wv[1],wv[2],wv[3]);
    } else {
        int id2 = idx - 7*4*64;
        int lane = id2 & 63, kt = (id2>>6)&3, nt = id2>>8;
        int n = nt*16 + (lane&15);
        int kb = kt*32 + (lane>>4)*8;
        unsigned wv[4];
        #pragma unroll
        for (int p = 0; p < 4; ++p) {
            int k0 = kb+2*p, k1 = kb+2*p+1;
            float v0 = (k0 < H_) ? W2[k0*T_ + n] : 0.f;
            float v1 = (k1 < H_) ? W2[k1*T_ + n] : 0.f;
            wv[p] = f2bf1(v0) | (f2bf1(v1) << 16);
        }
        W2f[id2] = make_uint4(wv[0],wv[1],wv[2],wv[3]);
    }
}

// ---------------------------------------------------------------------------
// FUSED kernel: per block (batch b), wave0 = fwd scan t=0..255, wave1 = bwd
// scan t=511..256 (r14 bidirectional fp16-broadcast scan, verbatim step body).
// Each wave PRODUCES its own em rows in 16-row batches (mlp MFMA pipeline,
// verbatim math) into a 4-slot LDS ring — em never touches global memory.
// Gathers for batch p+2 are issued one iteration ahead (vmcnt, ~19K cyc in
// flight); production compute (~2.5K cyc) runs between 16-step scan bursts.
// No cross-block deps / flags — dispatch-order-immune (unlike r9).
// ---------------------------------------------------------------------------
__global__ __launch_bounds__(128)
__attribute__((amdgpu_waves_per_eu(1, 1)))
void fused_kernel(
    const int* __restrict__ inputs, const int* __restrict__ tags,
    const unsigned short* __restrict__ tblh,
    const float* __restrict__ b1, const float* __restrict__ b2,
    const uint4* __restrict__ W1f, const uint4* __restrict__ W2f,
    const float* __restrict__ start_trans, const float* __restrict__ end_trans,
    const float* __restrict__ trans, float* __restrict__ out)
{
    __shared__ uint4 sW1f[1792];                         // 28 KB
    __shared__ uint4 sW2f[1024];                         // 16 KB
    __shared__ __align__(16) unsigned short ring[2][4][512];  // 8 KB
    __shared__ uint4 sA2[2][256];                        // 8 KB (A2 frags + tbuf alias)
    __shared__ __align__(16) _Float16 pbufH[2][T_];
    __shared__ float pubB[T_];
    __shared__ float fnum[2];
    __shared__ int   icnt[2];
    __shared__ float lsB_sh;

    const int b   = blockIdx.x;
    const int tid = threadIdx.x;
    const int w   = tid >> 6;            // 0 = fwd wave, 1 = bwd wave
    const int j   = tid & 63;
    const int col = j & 15;
    const int hi  = j >> 4;
    const int rowin = hi * 4;
    const int* tags_b = tags + b*S_;
    const int* in_b   = inputs + (size_t)b*S_*3;

    // stage W fragments (shared by both waves)
    for (int i = tid; i < 1792; i += 128) sW1f[i] = W1f[i];
    for (int i = tid; i < 1024; i += 128) sW2f[i] = W2f[i];

    // ---- mask ballots for THIS wave's half (t in [w*256, w*256+255]) ----
    unsigned long long mball[4];
    #pragma unroll
    for (int g4 = 0; g4 < 4; ++g4) {
        int t = (w*4 + g4)*64 + j;
        int a0 = in_b[t*3+0], a1 = in_b[t*3+1], a2 = in_b[t*3+2];
        mball[g4] = __ballot((a0 | a1 | a2) != 0);
    }
    int cnt = 0;
    #pragma unroll
    for (int g4 = 0; g4 < 4; ++g4) cnt += __popcll(mball[g4]);
    if (j == 0) icnt[w] = cnt;
    if (w == 0) mball[0] &= ~1ull;       // t=0 is not a scan step

    __syncthreads();                     // sW visible to both waves

    // preload biases (per-lane slices)
    float bv1[7], bv2[4];
    #pragma unroll
    for (int nt = 0; nt < 7; ++nt) { int n = nt*16+col; bv1[nt] = (n < H_) ? b1[n] : 0.f; }
    #pragma unroll
    for (int nt2 = 0; nt2 < 4; ++nt2) bv2[nt2] = b2[nt2*16+col];

    // E pairs in fp16: fwd = E column j; bwd = E row j
    h2 E2[32];
    #pragma unroll
    for (int i = 0; i < 32; ++i) {
        h2 e;
        if (w == 0) { e.x = (_Float16)__expf(trans[(2*i)*T_ + j]);
                      e.y = (_Float16)__expf(trans[(2*i+1)*T_ + j]); }
        else        { e.x = (_Float16)__expf(trans[j*T_ + 2*i]);
                      e.y = (_Float16)__expf(trans[j*T_ + 2*i+1]); }
        E2[i] = e;
    }

    // batch p (0..15) covers 16 consecutive rows; fwd ascending, bwd descending
    auto baseOf = [&](int p){ return w ? (480 - 16*p) : 16*p; };

    float np = 0.f;                      // numerator partial (this wave's half)

    auto loadIdx = [&](int p, int& x, int& y, int& z){
        size_t rgg = (size_t)b*S_ + (size_t)(baseOf(p) + col);
        x = in_b[(rgg - (size_t)b*S_)*3 + 0];   // == inputs[rgg*3+..]
        y = in_b[(rgg - (size_t)b*S_)*3 + 1];
        z = in_b[(rgg - (size_t)b*S_)*3 + 2];
    };
    auto issueGathers = [&](int i0, int i1, int i2, uint4* g){
        const unsigned short* tr0 = tblh + (size_t)i0*E_;
        const unsigned short* tr1 = tblh + (size_t)i1*E_;
        const unsigned short* tr2 = tblh + (size_t)i2*E_;
        #pragma unroll
        for (int kt = 0; kt < 4; ++kt) {
            int off = kt*32 + hi*8;
            g[kt*3+0] = *(const uint4*)(tr0 + off);
            g[kt*3+1] = *(const uint4*)(tr1 + off);
            g[kt*3+2] = *(const uint4*)(tr2 + off);
        }
    };

    // production: 16 rows (2 groups) -> ring slots; + numerator extraction
    auto produce = [&](int p, const uint4* g){
        U16x4 a[4];
        #pragma unroll
        for (int kt = 0; kt < 4; ++kt)
            a[kt].u = make_uint4(
                addpack3(g[kt*3+0].x, g[kt*3+1].x, g[kt*3+2].x),
                addpack3(g[kt*3+0].y, g[kt*3+1].y, g[kt*3+2].y),
                addpack3(g[kt*3+0].z, g[kt*3+1].z, g[kt*3+2].z),
                addpack3(g[kt*3+0].w, g[kt*3+1].w, g[kt*3+2].w));

        f32x4 acc1[7];
        #pragma unroll
        for (int nt = 0; nt < 7; ++nt) {
            f32x4 c; c[0]=bv1[nt]; c[1]=bv1[nt]; c[2]=bv1[nt]; c[3]=bv1[nt];
            #pragma unroll
            for (int k = 0; k < 4; ++k) {
                U16x4 bfr; bfr.u = sW1f[(nt*4+k)*64 + j];
                c = __builtin_amdgcn_mfma_f32_16x16x32_bf16(a[k].s, bfr.s, c, 0,0,0);
            }
            acc1[nt] = c;
        }
        #pragma unroll
        for (int nt = 0; nt < 7; ++nt)
            #pragma unroll
            for (int rr = 0; rr < 4; ++rr) {
                float x = acc1[nt][rr];
                acc1[nt][rr] = 1.f - 2.f/(__expf(2.f*x)+1.f);
            }

        if (j >= 32) sA2[w][3*64 + j] = make_uint4(0,0,0,0);
        unsigned short* A2h = (unsigned short*)sA2[w];
        #pragma unroll
        for (int nt = 0; nt < 7; ++nt)
            #pragma unroll
            for (int rr = 0; rr < 4; ++rr) {
                int k2 = nt*16 + col;
                int kt2 = k2 >> 5, g2 = (k2>>3)&3, i2v = k2&7;
                int u4idx = kt2*64 + g2*16 + (rowin + rr);
                A2h[u4idx*8 + i2v] = (unsigned short)f2bf1(acc1[nt][rr]);
            }
        __builtin_amdgcn_wave_barrier();

        U16x4 a2[4];
        #pragma unroll
        for (int k = 0; k < 4; ++k) a2[k].u = sA2[w][k*64 + j];
        __builtin_amdgcn_wave_barrier();

        unsigned short* tbuf = (unsigned short*)sA2[w];  // 16 x 72 shorts
        #pragma unroll
        for (int nt2 = 0; nt2 < 4; ++nt2) {
            f32x4 c; c[0]=bv2[nt2]; c[1]=bv2[nt2]; c[2]=bv2[nt2]; c[3]=bv2[nt2];
            #pragma unroll
            for (int k = 0; k < 4; ++k) {
                U16x4 bfr; bfr.u = sW2f[(nt2*4+k)*64 + j];
                c = __builtin_amdgcn_mfma_f32_16x16x32_bf16(a2[k].s, bfr.s, c, 0,0,0);
            }
            #pragma unroll
            for (int rr = 0; rr < 4; ++rr)
                tbuf[(rowin+rr)*72 + nt2*16 + col] = (unsigned short)f2bf1(c[rr]);
        }
        __builtin_amdgcn_wave_barrier();

        {   // ring write (row-major group rows)
            const int rl = j >> 2;
            const int ch = (j & 3) * 2;
            const uint4* t4 = (const uint4*)tbuf;
            uint4 u0 = t4[rl*9 + ch];
            uint4 u1 = t4[rl*9 + ch + 1];
            int row = baseOf(p) + rl;                    // absolute t
            int grp = row >> 3;
            int kidx = w ? (63 - grp) : grp;             // wave-local group
            uint4* dst = (uint4*)&ring[w][kidx & 3][(row & 7)*64];
            dst[ch]   = u0;
            dst[ch+1] = u1;
        }
        __builtin_amdgcn_wave_barrier();

        // numerator extraction for these 16 rows
        if (j < 16) {
            int t = baseOf(p) + j;
            if (t >= 1) {
                int word = (t >> 6) - w*4;
                if ((mball[word] >> (t & 63)) & 1ull) {
                    int tp = tags_b[t-1], tc = tags_b[t];
                    int grp = t >> 3;
                    int kidx = w ? (63 - grp) : grp;
                    np += trans[tp*T_ + tc] + bf2f(ring[w][kidx & 3][(t & 7)*64 + tc]);
                }
            }
        }
    };

    // ---- prologue: produce batches 0,1; batch-2 gathers + batch-3 idx in flight
    uint4 g[12];
    int i0, i1, i2, ni0, ni1, ni2;
    loadIdx(0, i0, i1, i2);
    issueGathers(i0, i1, i2, g);
    produce(0, g);
    // t=0 terms + fwd init (group 0 now in ring slot 0)
    float a, ls;
    if (w == 0) {
        if (j == 0) {
            int tag0 = tags_b[0];
            np += start_trans[tag0] + bf2f(ring[0][0][tag0]);
        }
        float x0v = start_trans[j] + bf2f(ring[0][0][j]);
        ls = rfl_f(x0v);
        a  = __expf(x0v - ls);
    } else {
        a  = __expf(end_trans[j]);
        ls = 0.f;
    }
    loadIdx(1, i0, i1, i2);
    issueGathers(i0, i1, i2, g);
    produce(1, g);
    loadIdx(2, i0, i1, i2);
    issueGathers(i0, i1, i2, g);     // batch 2 in flight
    loadIdx(3, ni0, ni1, ni2);       // batch 3 idx in flight

    // eg for group 0
    float eg[8];
    #pragma unroll
    for (int s = 0; s < 8; ++s)
        eg[s] = __expf(bf2f(ring[w][0][(w ? (7-s) : s)*64 + j]));

    // ---- main loop: 16 iterations x (2 groups x 8 steps) + pipelined prod
    for (int p = 0; p < 16; ++p) {
        #pragma unroll
        for (int kk = 0; kk < 2; ++kk) {
            const int k = 2*p + kk;
            unsigned short raw16[8];
            if (k < 31) {
                const unsigned short* nxt = ring[w][(k+1) & 3];
                #pragma unroll
                for (int s = 0; s < 8; ++s)
                    raw16[s] = nxt[(w ? (7-s) : s)*64 + j];
            }
            const int ag = w ? (63 - k) : k;
            const unsigned mg = (unsigned)((mball[(ag>>3) - w*4] >> ((ag&7)*8)) & 0xFFull);

            #pragma unroll
            for (int s = 0; s < 8; ++s) {
                float wv = (w == 0) ? a : (eg[s] * a);
                pbufH[w][j] = (_Float16)(wv * 0.015625f);
                __builtin_amdgcn_wave_barrier();
                float sc   = rfl_f(a);
                float sinv = __builtin_amdgcn_rcpf(sc);
                float logs = __logf(sc);
                float keep = a * sinv;
                float dmul = ((w == 0) ? (eg[s] * sinv) : sinv) * 64.0f;

                const uint4* ph = (const uint4*)pbufH[w];
                float ac0=0.f, ac1=0.f, ac2=0.f, ac3=0.f;
                #pragma unroll
                for (int q = 0; q < 8; ++q) {
                    uint4 U = ph[q];
                    ac0 = fdot2h(U.x, E2[4*q+0], ac0);
                    ac1 = fdot2h(U.y, E2[4*q+1], ac1);
                    ac2 = fdot2h(U.z, E2[4*q+2], ac2);
                    ac3 = fdot2h(U.w, E2[4*q+3], ac3);
                }
                float dot = (ac0+ac1)+(ac2+ac3);
                float cand = dot * dmul;
                const int bit = (w == 0) ? s : (7 - s);
                a = ((mg >> bit) & 1u) ? cand : keep;
                ls += logs;
                __builtin_amdgcn_wave_barrier();
            }
            if (k < 31) {
                #pragma unroll
                for (int s = 0; s < 8; ++s) eg[s] = __expf(bf2f(raw16[s]));
            }
        }
        if (p <= 13) produce(p + 2, g);
        if (p <= 12) {
            issueGathers(ni0, ni1, ni2, g);          // batch p+3
            if (p <= 11) loadIdx(p + 4, ni0, ni1, ni2);
        }
    }

    // ---- numerator reduce + merge ----
    #pragma unroll
    for (int off = 32; off >= 1; off >>= 1) np += __shfl_xor(np, off, 64);
    if (j == 0) fnum[w] = np;

    if (w == 1) {
        pubB[j] = a;
        if (j == 0) lsB_sh = ls;
    }
    __syncthreads();
    if (w == 0) {
        float x = a * pubB[j];
        #pragma unroll
        for (int off = 32; off >= 1; off >>= 1) x += __shfl_xor(x, off, 64);
        int mcount = icnt[0] + icnt[1];
        int se = mcount - 1; if (se < 0) se = 0;
        const int last_tag = tags_b[se];
        float numer = fnum[0] + fnum[1] + end_trans[last_tag];
        if (j == 0) out[b] = ls + lsB_sh + __logf(x) - numer;
    }
}

// ---------------------------------------------------------------------------
extern "C" void kernel_launch(void* const* d_in, const int* in_sizes, int n_in,
                              void* d_out, int out_size, void* d_ws, size_t ws_size,
                              hipStream_t stream) {
    const int*   inputs      = (const int*)  d_in[0];
    const int*   tags        = (const int*)  d_in[1];
    const float* emb_table   = (const float*)d_in[2];
    const float* W1          = (const float*)d_in[3];
    const float* b1          = (const float*)d_in[4];
    const float* W2          = (const float*)d_in[5];
    const float* b2          = (const float*)d_in[6];
    const float* start_trans = (const float*)d_in[7];
    const float* end_trans   = (const float*)d_in[8];
    const float* transitions = (const float*)d_in[9];
    float* out = (float*)d_out;

    // ws: tblh bf16 (25.6 MB) | W1f (28 KB) | W2f (16 KB)   — em eliminated
    unsigned short* tblh = (unsigned short*)d_ws;
    uint4* W1f = (uint4*)((char*)d_ws + (size_t)V_*E_*2);
    uint4* W2f = W1f + 7*4*64;

    prep_tbl<<<dim3((V_*E_/4 + 255)/256), dim3(256), 0, stream>>>(emb_table, (uint2*)tblh);
    prep_w<<<dim3((7*4*64 + 4*4*64)/64), dim3(64), 0, stream>>>(W1, W2, W1f, W2f);
    fused_kernel<<<dim3(B_), dim3(128), 0, stream>>>(
        inputs, tags, tblh, b1, b2, W1f, W2f,
        start_trans, end_trans, transitions, out);
}

// Round 16
// 222.360 us; speedup vs baseline: 1.5733x; 1.0774x over previous
//
#include <hip/hip_runtime.h>

#define B_ 512
#define S_ 512
#define E_ 128
#define H_ 100
#define T_ 64
#define V_ 100000
#define BS_ (B_*S_)

typedef __attribute__((ext_vector_type(8))) short bf16x8;
typedef __attribute__((ext_vector_type(4))) float f32x4;
typedef _Float16 h2 __attribute__((ext_vector_type(2)));
union U16x4 { uint4 u; bf16x8 s; };

__device__ __forceinline__ unsigned f2bf1(float x){
    unsigned u = __float_as_uint(x);
    return (u + 0x7FFFu + ((u>>16)&1u)) >> 16;
}
__device__ __forceinline__ float bf2f(unsigned short h){
    return __uint_as_float(((unsigned)h)<<16);
}
__device__ __forceinline__ float rfl_f(float x){
    return __uint_as_float(__builtin_amdgcn_readfirstlane(__float_as_uint(x)));
}
__device__ __forceinline__ unsigned addpack3(unsigned a, unsigned b, unsigned c){
    float lo = __uint_as_float(a<<16) + __uint_as_float(b<<16) + __uint_as_float(c<<16);
    float hi = __uint_as_float(a&0xFFFF0000u) + __uint_as_float(b&0xFFFF0000u)
             + __uint_as_float(c&0xFFFF0000u);
    return f2bf1(lo) | (f2bf1(hi)<<16);
}
__device__ __forceinline__ float fdot2h(unsigned u, h2 e, float c){
    h2 p; __builtin_memcpy(&p, &u, 4);
#if __has_builtin(__builtin_amdgcn_fdot2)
    return __builtin_amdgcn_fdot2(p, e, c, false);
#else
    return fmaf((float)p.x, (float)e.x, fmaf((float)p.y, (float)e.y, c));
#endif
}
// quad_perm DPP cross-lane (VALU path — NOT a DS op): xor1=[1,0,3,2], xor2=[2,3,0,1]
__device__ __forceinline__ float dpp_xor1(float x){
    return __int_as_float(__builtin_amdgcn_mov_dpp(__float_as_int(x), 0xB1, 0xF, 0xF, true));
}
__device__ __forceinline__ float dpp_xor2(float x){
    return __int_as_float(__builtin_amdgcn_mov_dpp(__float_as_int(x), 0x4E, 0xF, 0xF, true));
}

// ---------------------------------------------------------------------------
// prep_tbl: fp32 emb table -> bf16 copy.
// ---------------------------------------------------------------------------
__global__ __launch_bounds__(256) void prep_tbl(
    const float* __restrict__ tbl, uint2* __restrict__ tblh)
{
    int idx = blockIdx.x*256 + threadIdx.x;
    if (idx < (V_*E_)/4) {
        float4 v = ((const float4*)tbl)[idx];
        uint2 o;
        o.x = f2bf1(v.x) | (f2bf1(v.y)<<16);
        o.y = f2bf1(v.z) | (f2bf1(v.w)<<16);
        tblh[idx] = o;
    }
}

// ---------------------------------------------------------------------------
// prep_w: W1/W2 bf16 MFMA B-fragment images.
// ---------------------------------------------------------------------------
__global__ __launch_bounds__(64) void prep_w(
    const float* __restrict__ W1, const float* __restrict__ W2,
    uint4* __restrict__ W1f, uint4* __restrict__ W2f)
{
    const int idx = blockIdx.x*64 + threadIdx.x;
    if (idx < 7*4*64) {
        int lane = idx & 63, kt = (idx>>6)&3, nt = idx>>8;
        int n = nt*16 + (lane&15);
        int kb = kt*32 + (lane>>4)*8;
        unsigned wv[4];
        #pragma unroll
        for (int p = 0; p < 4; ++p) {
            float v0 = (n < H_) ? W1[(kb+2*p  )*H_ + n] : 0.f;
            float v1 = (n < H_) ? W1[(kb+2*p+1)*H_ + n] : 0.f;
            wv[p] = f2bf1(v0) | (f2bf1(v1) << 16);
        }
        W1f[idx] = make_uint4(wv[0],wv[1],wv[2],wv[3]);
    } else {
        int id2 = idx - 7*4*64;
        int lane = id2 & 63, kt = (id2>>6)&3, nt = id2>>8;
        int n = nt*16 + (lane&15);
        int kb = kt*32 + (lane>>4)*8;
        unsigned wv[4];
        #pragma unroll
        for (int p = 0; p < 4; ++p) {
            int k0 = kb+2*p, k1 = kb+2*p+1;
            float v0 = (k0 < H_) ? W2[k0*T_ + n] : 0.f;
            float v1 = (k1 < H_) ? W2[k1*T_ + n] : 0.f;
            wv[p] = f2bf1(v0) | (f2bf1(v1) << 16);
        }
        W2f[id2] = make_uint4(wv[0],wv[1],wv[2],wv[3]);
    }
}

// ---------------------------------------------------------------------------
// FUSED kernel (r15 structure). ROUND 16 change: scan matvec split 4-ways —
// lane j (quad g=j>>2, slot m=j&3) reads ONLY its 16-value input slice
// (2x ds_read_b128), computes partials for its quad's 4 outputs, then
// reduce-scatters via quad_perm DPP (VALU, no DS). DS ops/step: 9 -> 3.
// r4..r15 evidence: scan is DS-issue/queue-bound (LDS pipe at 28-43 B/cyc,
// far under limit), so op count — not bytes — is the lever.
// ---------------------------------------------------------------------------
__global__ __launch_bounds__(128)
__attribute__((amdgpu_waves_per_eu(1, 1)))
void fused_kernel(
    const int* __restrict__ inputs, const int* __restrict__ tags,
    const unsigned short* __restrict__ tblh,
    const float* __restrict__ b1, const float* __restrict__ b2,
    const uint4* __restrict__ W1f, const uint4* __restrict__ W2f,
    const float* __restrict__ start_trans, const float* __restrict__ end_trans,
    const float* __restrict__ trans, float* __restrict__ out)
{
    __shared__ uint4 sW1f[1792];                         // 28 KB
    __shared__ uint4 sW2f[1024];                         // 16 KB
    __shared__ __align__(16) unsigned short ring[2][4][512];  // 8 KB
    __shared__ uint4 sA2[2][256];                        // 8 KB
    __shared__ __align__(16) _Float16 pbufH[2][T_];
    __shared__ float pubB[T_];
    __shared__ float fnum[2];
    __shared__ int   icnt[2];
    __shared__ float lsB_sh;

    const int b   = blockIdx.x;
    const int tid = threadIdx.x;
    const int w   = tid >> 6;            // 0 = fwd wave, 1 = bwd wave
    const int j   = tid & 63;
    const int col = j & 15;
    const int hi  = j >> 4;
    const int rowin = hi * 4;
    const int qg  = j >> 2;              // quad (output group: 4 outputs)
    const int qm  = j & 3;               // slot (input slice: 16 inputs)
    const bool qb0 = (j & 1) != 0;
    const bool qb1 = (j & 2) != 0;
    const int* tags_b = tags + b*S_;
    const int* in_b   = inputs + (size_t)b*S_*3;

    for (int i = tid; i < 1792; i += 128) sW1f[i] = W1f[i];
    for (int i = tid; i < 1024; i += 128) sW2f[i] = W2f[i];

    // ---- mask ballots for THIS wave's half ----
    unsigned long long mball[4];
    #pragma unroll
    for (int g4 = 0; g4 < 4; ++g4) {
        int t = (w*4 + g4)*64 + j;
        int a0 = in_b[t*3+0], a1 = in_b[t*3+1], a2 = in_b[t*3+2];
        mball[g4] = __ballot((a0 | a1 | a2) != 0);
    }
    int cnt = 0;
    #pragma unroll
    for (int g4 = 0; g4 < 4; ++g4) cnt += __popcll(mball[g4]);
    if (j == 0) icnt[w] = cnt;
    if (w == 0) mball[0] &= ~1ull;

    __syncthreads();

    float bv1[7], bv2[4];
    #pragma unroll
    for (int nt = 0; nt < 7; ++nt) { int n = nt*16+col; bv1[nt] = (n < H_) ? b1[n] : 0.f; }
    #pragma unroll
    for (int nt2 = 0; nt2 < 4; ++nt2) bv2[nt2] = b2[nt2*16+col];

    // E slice in fp16: 4 outputs (quad) x 16 inputs (slot) = 32 h2
    // fwd: y_j = sum_i E[i][j] x_i ;  bwd: y_j = sum_i E[j][i] x_i
    h2 E2[32];
    #pragma unroll
    for (int o = 0; o < 4; ++o)
        #pragma unroll
        for (int i = 0; i < 8; ++i) {
            int r0, c0, r1, c1;
            if (w == 0) { r0 = 16*qm + 2*i; c0 = 4*qg + o; r1 = r0 + 1; c1 = c0; }
            else        { r0 = 4*qg + o; c0 = 16*qm + 2*i; r1 = r0; c1 = c0 + 1; }
            h2 e; e.x = (_Float16)__expf(trans[r0*T_ + c0]);
                  e.y = (_Float16)__expf(trans[r1*T_ + c1]);
            E2[o*8 + i] = e;
        }

    auto baseOf = [&](int p){ return w ? (480 - 16*p) : 16*p; };
    float np = 0.f;

    auto loadIdx = [&](int p, int& x, int& y, int& z){
        int t = baseOf(p) + col;
        x = in_b[t*3 + 0]; y = in_b[t*3 + 1]; z = in_b[t*3 + 2];
    };
    auto issueGathers = [&](int i0, int i1, int i2, uint4* g){
        const unsigned short* tr0 = tblh + (size_t)i0*E_;
        const unsigned short* tr1 = tblh + (size_t)i1*E_;
        const unsigned short* tr2 = tblh + (size_t)i2*E_;
        #pragma unroll
        for (int kt = 0; kt < 4; ++kt) {
            int off = kt*32 + hi*8;
            g[kt*3+0] = *(const uint4*)(tr0 + off);
            g[kt*3+1] = *(const uint4*)(tr1 + off);
            g[kt*3+2] = *(const uint4*)(tr2 + off);
        }
    };

    auto produce = [&](int p, const uint4* g){
        U16x4 a[4];
        #pragma unroll
        for (int kt = 0; kt < 4; ++kt)
            a[kt].u = make_uint4(
                addpack3(g[kt*3+0].x, g[kt*3+1].x, g[kt*3+2].x),
                addpack3(g[kt*3+0].y, g[kt*3+1].y, g[kt*3+2].y),
                addpack3(g[kt*3+0].z, g[kt*3+1].z, g[kt*3+2].z),
                addpack3(g[kt*3+0].w, g[kt*3+1].w, g[kt*3+2].w));

        f32x4 acc1[7];
        #pragma unroll
        for (int nt = 0; nt < 7; ++nt) {
            f32x4 c; c[0]=bv1[nt]; c[1]=bv1[nt]; c[2]=bv1[nt]; c[3]=bv1[nt];
            #pragma unroll
            for (int k = 0; k < 4; ++k) {
                U16x4 bfr; bfr.u = sW1f[(nt*4+k)*64 + j];
                c = __builtin_amdgcn_mfma_f32_16x16x32_bf16(a[k].s, bfr.s, c, 0,0,0);
            }
            acc1[nt] = c;
        }
        #pragma unroll
        for (int nt = 0; nt < 7; ++nt)
            #pragma unroll
            for (int rr = 0; rr < 4; ++rr) {
                float x = acc1[nt][rr];
                acc1[nt][rr] = 1.f - 2.f/(__expf(2.f*x)+1.f);
            }

        if (j >= 32) sA2[w][3*64 + j] = make_uint4(0,0,0,0);
        unsigned short* A2h = (unsigned short*)sA2[w];
        #pragma unroll
        for (int nt = 0; nt < 7; ++nt)
            #pragma unroll
            for (int rr = 0; rr < 4; ++rr) {
                int k2 = nt*16 + col;
                int kt2 = k2 >> 5, g2 = (k2>>3)&3, i2v = k2&7;
                int u4idx = kt2*64 + g2*16 + (rowin + rr);
                A2h[u4idx*8 + i2v] = (unsigned short)f2bf1(acc1[nt][rr]);
            }
        __builtin_amdgcn_wave_barrier();

        U16x4 a2[4];
        #pragma unroll
        for (int k = 0; k < 4; ++k) a2[k].u = sA2[w][k*64 + j];
        __builtin_amdgcn_wave_barrier();

        unsigned short* tbuf = (unsigned short*)sA2[w];
        #pragma unroll
        for (int nt2 = 0; nt2 < 4; ++nt2) {
            f32x4 c; c[0]=bv2[nt2]; c[1]=bv2[nt2]; c[2]=bv2[nt2]; c[3]=bv2[nt2];
            #pragma unroll
            for (int k = 0; k < 4; ++k) {
                U16x4 bfr; bfr.u = sW2f[(nt2*4+k)*64 + j];
                c = __builtin_amdgcn_mfma_f32_16x16x32_bf16(a2[k].s, bfr.s, c, 0,0,0);
            }
            #pragma unroll
            for (int rr = 0; rr < 4; ++rr)
                tbuf[(rowin+rr)*72 + nt2*16 + col] = (unsigned short)f2bf1(c[rr]);
        }
        __builtin_amdgcn_wave_barrier();

        {
            const int rl = j >> 2;
            const int ch = (j & 3) * 2;
            const uint4* t4 = (const uint4*)tbuf;
            uint4 u0 = t4[rl*9 + ch];
            uint4 u1 = t4[rl*9 + ch + 1];
            int row = baseOf(p) + rl;
            int grp = row >> 3;
            int kidx = w ? (63 - grp) : grp;
            uint4* dst = (uint4*)&ring[w][kidx & 3][(row & 7)*64];
            dst[ch]   = u0;
            dst[ch+1] = u1;
        }
        __builtin_amdgcn_wave_barrier();

        if (j < 16) {
            int t = baseOf(p) + j;
            if (t >= 1) {
                int word = (t >> 6) - w*4;
                if ((mball[word] >> (t & 63)) & 1ull) {
                    int tp = tags_b[t-1], tc = tags_b[t];
                    int grp = t >> 3;
                    int kidx = w ? (63 - grp) : grp;
                    np += trans[tp*T_ + tc] + bf2f(ring[w][kidx & 3][(t & 7)*64 + tc]);
                }
            }
        }
    };

    // ---- prologue ----
    uint4 g[12];
    int i0, i1, i2, ni0, ni1, ni2;
    loadIdx(0, i0, i1, i2);
    issueGathers(i0, i1, i2, g);
    produce(0, g);
    float a, ls;
    if (w == 0) {
        if (j == 0) {
            int tag0 = tags_b[0];
            np += start_trans[tag0] + bf2f(ring[0][0][tag0]);
        }
        float x0v = start_trans[j] + bf2f(ring[0][0][j]);
        ls = rfl_f(x0v);
        a  = __expf(x0v - ls);
    } else {
        a  = __expf(end_trans[j]);
        ls = 0.f;
    }
    loadIdx(1, i0, i1, i2);
    issueGathers(i0, i1, i2, g);
    produce(1, g);
    loadIdx(2, i0, i1, i2);
    issueGathers(i0, i1, i2, g);
    loadIdx(3, ni0, ni1, ni2);

    float eg[8];
    #pragma unroll
    for (int s = 0; s < 8; ++s)
        eg[s] = __expf(bf2f(ring[w][0][(w ? (7-s) : s)*64 + j]));

    // ---- main loop ----
    for (int p = 0; p < 16; ++p) {
        #pragma unroll
        for (int kk = 0; kk < 2; ++kk) {
            const int k = 2*p + kk;
            unsigned short raw16[8];
            if (k < 31) {
                const unsigned short* nxt = ring[w][(k+1) & 3];
                #pragma unroll
                for (int s = 0; s < 8; ++s)
                    raw16[s] = nxt[(w ? (7-s) : s)*64 + j];
            }
            const int ag = w ? (63 - k) : k;
            const unsigned mg = (unsigned)((mball[(ag>>3) - w*4] >> ((ag&7)*8)) & 0xFFull);

            #pragma unroll
            for (int s = 0; s < 8; ++s) {
                float wv = (w == 0) ? a : (eg[s] * a);
                pbufH[w][j] = (_Float16)(wv * 0.015625f);
                __builtin_amdgcn_wave_barrier();
                float sc   = rfl_f(a);
                float sinv = __builtin_amdgcn_rcpf(sc);
                float logs = __logf(sc);
                float keep = a * sinv;
                float dmul = ((w == 0) ? (eg[s] * sinv) : sinv) * 64.0f;

                // 2x b128: this lane's 16-input slice
                const uint4* ph = (const uint4*)pbufH[w];
                uint4 U0 = ph[2*qm];
                uint4 U1 = ph[2*qm + 1];
                float p0, p1, p2, p3;
                p0 = fdot2h(U0.x, E2[ 0], 0.f);  p0 = fdot2h(U0.y, E2[ 1], p0);
                p0 = fdot2h(U0.z, E2[ 2], p0);   p0 = fdot2h(U0.w, E2[ 3], p0);
                p0 = fdot2h(U1.x, E2[ 4], p0);   p0 = fdot2h(U1.y, E2[ 5], p0);
                p0 = fdot2h(U1.z, E2[ 6], p0);   p0 = fdot2h(U1.w, E2[ 7], p0);
                p1 = fdot2h(U0.x, E2[ 8], 0.f);  p1 = fdot2h(U0.y, E2[ 9], p1);
                p1 = fdot2h(U0.z, E2[10], p1);   p1 = fdot2h(U0.w, E2[11], p1);
                p1 = fdot2h(U1.x, E2[12], p1);   p1 = fdot2h(U1.y, E2[13], p1);
                p1 = fdot2h(U1.z, E2[14], p1);   p1 = fdot2h(U1.w, E2[15], p1);
                p2 = fdot2h(U0.x, E2[16], 0.f);  p2 = fdot2h(U0.y, E2[17], p2);
                p2 = fdot2h(U0.z, E2[18], p2);   p2 = fdot2h(U0.w, E2[19], p2);
                p2 = fdot2h(U1.x, E2[20], p2);   p2 = fdot2h(U1.y, E2[21], p2);
                p2 = fdot2h(U1.z, E2[22], p2);   p2 = fdot2h(U1.w, E2[23], p2);
                p3 = fdot2h(U0.x, E2[24], 0.f);  p3 = fdot2h(U0.y, E2[25], p3);
                p3 = fdot2h(U0.z, E2[26], p3);   p3 = fdot2h(U0.w, E2[27], p3);
                p3 = fdot2h(U1.x, E2[28], p3);   p3 = fdot2h(U1.y, E2[29], p3);
                p3 = fdot2h(U1.z, E2[30], p3);   p3 = fdot2h(U1.w, E2[31], p3);

                // quad reduce-scatter via DPP: lane j ends with y_j
                float t0 = qb1 ? p2 : p0;
                float t1 = qb1 ? p3 : p1;
                float s0 = qb1 ? p0 : p2;
                float s1 = qb1 ? p1 : p3;
                t0 += dpp_xor2(s0);
                t1 += dpp_xor2(s1);
                float tt = qb0 ? t1 : t0;
                float ss = qb0 ? t0 : t1;
                float y  = tt + dpp_xor1(ss);

                float cand = y * dmul;
                const int bit = (w == 0) ? s : (7 - s);
                a = ((mg >> bit) & 1u) ? cand : keep;
                ls += logs;
                __builtin_amdgcn_wave_barrier();
            }
            if (k < 31) {
                #pragma unroll
                for (int s = 0; s < 8; ++s) eg[s] = __expf(bf2f(raw16[s]));
            }
        }
        if (p <= 13) produce(p + 2, g);
        if (p <= 12) {
            issueGathers(ni0, ni1, ni2, g);
            if (p <= 11) loadIdx(p + 4, ni0, ni1, ni2);
        }
    }

    // ---- numerator reduce + merge ----
    #pragma unroll
    for (int off = 32; off >= 1; off >>= 1) np += __shfl_xor(np, off, 64);
    if (j == 0) fnum[w] = np;

    if (w == 1) {
        pubB[j] = a;
        if (j == 0) lsB_sh = ls;
    }
    __syncthreads();
    if (w == 0) {
        float x = a * pubB[j];
        #pragma unroll
        for (int off = 32; off >= 1; off >>= 1) x += __shfl_xor(x, off, 64);
        int mcount = icnt[0] + icnt[1];
        int se = mcount - 1; if (se < 0) se = 0;
        const int last_tag = tags_b[se];
        float numer = fnum[0] + fnum[1] + end_trans[last_tag];
        if (j == 0) out[b] = ls + lsB_sh + __logf(x) - numer;
    }
}

// ---------------------------------------------------------------------------
extern "C" void kernel_launch(void* const* d_in, const int* in_sizes, int n_in,
                              void* d_out, int out_size, void* d_ws, size_t ws_size,
                              hipStream_t stream) {
    const int*   inputs      = (const int*)  d_in[0];
    const int*   tags        = (const int*)  d_in[1];
    const float* emb_table   = (const float*)d_in[2];
    const float* W1          = (const float*)d_in[3];
    const float* b1          = (const float*)d_in[4];
    const float* W2          = (const float*)d_in[5];
    const float* b2          = (const float*)d_in[6];
    const float* start_trans = (const float*)d_in[7];
    const float* end_trans   = (const float*)d_in[8];
    const float* transitions = (const float*)d_in[9];
    float* out = (float*)d_out;

    // ws: tblh bf16 (25.6 MB) | W1f (28 KB) | W2f (16 KB)
    unsigned short* tblh = (unsigned short*)d_ws;
    uint4* W1f = (uint4*)((char*)d_ws + (size_t)V_*E_*2);
    uint4* W2f = W1f + 7*4*64;

    prep_tbl<<<dim3((V_*E_/4 + 255)/256), dim3(256), 0, stream>>>(emb_table, (uint2*)tblh);
    prep_w<<<dim3((7*4*64 + 4*4*64)/64), dim3(64), 0, stream>>>(W1, W2, W1f, W2f);
    fused_kernel<<<dim3(B_), dim3(128), 0, stream>>>(
        inputs, tags, tblh, b1, b2, W1f, W2f,
        start_trans, end_trans, transitions, out);
}